// Round 23
// baseline (163.571 us; speedup 1.0000x reference)
//
#include <hip/hip_runtime.h>
#include <hip/hip_bf16.h>

// Grapher block: RepCPE(dw7x7+res) -> fc1+BN -> MRConv4d(K=2) -> gc(2C->C)+BN+GELU -> fc2+BN
// B=32, C=192, H=W=56. d_in/d_out FLOAT32; intermediates bf16.
//
//   fold:   BN-fold weights -> W1f[192][192], Wgf[192][384], W2f[192][192] (bf16), biases fp32
//   dwconv: v12 = v10 + CG-BLOCKED y0 layout [b][12 cg][3136 px][16 ch] (full-line stores,
//           no cross-block L2 RMW) + 5 blocks/CU (launch_bounds(256,5))
//   gemm1:  template MODE 0, gl_lds staging from BLOCKED y0 source -> y1 bf16 pm (d_out)
//   gemm2:  768-thread, T14-split fused xj, tanh-GELU -> y2 bf16 pm (y0 buffer reused)
//   gemm3:  template MODE 2 (swapped ops), pixel-major y2 -> d_out f32 channel-major

#define CC   192
#define HW   3136
#define NB   32
#define CP_STR 957                             // dwords; -3 mod 32 (bank-conflict-free)

using short8 = __attribute__((ext_vector_type(8))) short;
using f32x4  = __attribute__((ext_vector_type(4))) float;
using f32x2  = __attribute__((ext_vector_type(2))) float;

__device__ __forceinline__ float bf2f(short s) {
  union { unsigned u; float f; } x; x.u = ((unsigned)(unsigned short)s) << 16; return x.f;
}
__device__ __forceinline__ short f2bf(float f) {
  __hip_bfloat16 h = __float2bfloat16(f);
  return *reinterpret_cast<short*>(&h);
}
__device__ __forceinline__ unsigned pack_bf2(float a, float b) {
  return ((unsigned)(unsigned short)f2bf(a)) | (((unsigned)(unsigned short)f2bf(b)) << 16);
}
__device__ __forceinline__ f32x2 up2(unsigned d) {
  union { unsigned u; float f; } lo, hi;
  lo.u = d << 16; hi.u = d & 0xffff0000u;
  f32x2 r; r.x = lo.f; r.y = hi.f; return r;
}
// packed dual-FP32 FMA: d = a*b + c elementwise on 2 floats (one instruction)
__device__ __forceinline__ f32x2 pk_fma(f32x2 a, f32x2 b, f32x2 c) {
  f32x2 d;
  asm("v_pk_fma_f32 %0, %1, %2, %3" : "=v"(d) : "v"(a), "v"(b), "v"(c));
  return d;
}
// tanh-form GELU: max |delta| vs erf-form ~1e-3 (<< 0.08 tol). Inf-safe: 2 - 2/(e+1).
__device__ __forceinline__ float geluf(float v) {
  float u = 0.7978845608028654f * (v + 0.044715f * v * v * v);
  float e = __expf(2.0f * u);
  return 0.5f * v * (2.0f - 2.0f / (e + 1.0f));
}
__device__ __forceinline__ void gl2lds(const char* g, char* l) {
  __builtin_amdgcn_global_load_lds(
      (const __attribute__((address_space(1))) void*)g,
      (__attribute__((address_space(3))) void*)l, 16, 0, 0);
}

// ---------------- fold: BN into weights/bias ----------------
__global__ void __launch_bounds__(256) fold_kernel(
    const float* __restrict__ fc1_w, const float* __restrict__ fc1_b,
    const float* __restrict__ bn1_g, const float* __restrict__ bn1_b,
    const float* __restrict__ bn1_m, const float* __restrict__ bn1_v,
    const float* __restrict__ gc_w,  const float* __restrict__ gc_b,
    const float* __restrict__ bng_g, const float* __restrict__ bng_b,
    const float* __restrict__ bng_m, const float* __restrict__ bng_v,
    const float* __restrict__ fc2_w, const float* __restrict__ fc2_b,
    const float* __restrict__ bn2_g, const float* __restrict__ bn2_b,
    const float* __restrict__ bn2_m, const float* __restrict__ bn2_v,
    __hip_bfloat16* __restrict__ W1f, __hip_bfloat16* __restrict__ Wgf, __hip_bfloat16* __restrict__ W2f,
    float* __restrict__ b1f, float* __restrict__ bgf, float* __restrict__ b2f) {
  int gt = blockIdx.x * 256 + threadIdx.x;
  if (gt < 3 * CC) {
    int which = gt / CC, o = gt - which * CC;
    const float *G, *Bt, *M, *V, *Bi; float* dst;
    if (which == 0)      { G = bn1_g; Bt = bn1_b; M = bn1_m; V = bn1_v; Bi = fc1_b; dst = b1f; }
    else if (which == 1) { G = bng_g; Bt = bng_b; M = bng_m; V = bng_v; Bi = gc_b;  dst = bgf; }
    else                 { G = bn2_g; Bt = bn2_b; M = bn2_m; V = bn2_v; Bi = fc2_b; dst = b2f; }
    float inv = G[o] * rsqrtf(V[o] + 1e-5f);
    dst[o] = Bi[o] * inv + Bt[o] - M[o] * inv;
  }
  int i = gt;
  if (i < CC * CC) {
    int o = i / CC;
    float inv = bn1_g[o] * rsqrtf(bn1_v[o] + 1e-5f);
    W1f[i] = __float2bfloat16(fc1_w[i] * inv);
  } else if (i < CC * CC + CC * 2 * CC) {
    int j = i - CC * CC; int o = j / (2 * CC);
    float inv = bng_g[o] * rsqrtf(bng_v[o] + 1e-5f);
    Wgf[j] = __float2bfloat16(gc_w[j] * inv);
  } else if (i < CC * CC * 4) {
    int j = i - CC * CC * 3; int o = j / CC;
    float inv = bn2_g[o] * rsqrtf(bn2_v[o] + 1e-5f);
    W2f[j] = __float2bfloat16(fc2_w[j] * inv);
  }
}

// ---------------- dw 7x7 + bias + residual -> CG-BLOCKED bf16 (v12) ----------------
// Output layout: y0b[b][cg=12][3136 px][16 ch]. Each block owns a contiguous private
// region -> every 128B L2 line written wholly by one block (no RMW at any occupancy).
__global__ void __launch_bounds__(256, 5) dwconv_kernel(
    const float* __restrict__ x, const float* __restrict__ cw,
    const float* __restrict__ cb, __hip_bfloat16* __restrict__ y0b) {
  __shared__ unsigned in_t2[8 * CP_STR];       // 30624 B
  const int t = threadIdx.x;
  int bb = blockIdx.x;
  const int rs = bb % 7;  bb /= 7;
  const int cg = bb % 12; bb /= 12;
  const int b  = bb;
  const int h0 = rs * 8;

  for (int i = t; i < 8 * CP_STR / 4; i += 256) ((uint4*)in_t2)[i] = uint4{0, 0, 0, 0};
  __syncthreads();

  // stage rows h0-3 .. h0+10 (14 rows), 8 channel-pairs, packed bf16x2
  for (int it = t; it < 8 * 14 * 14; it += 256) {
    int w4 = it % 14, rr = (it / 14) % 14, cp = it / 196;
    int gh = h0 - 3 + rr;
    if (gh >= 0 && gh < 56) {
      const float* pa = x + ((size_t)(b * CC + cg * 16 + cp * 2) * 56 + gh) * 56 + w4 * 4;
      float4 va = *(const float4*)pa;
      float4 vb = *(const float4*)(pa + 3136);   // next channel (56*56)
      uint4 u;
      u.x = pack_bf2(va.x, vb.x); u.y = pack_bf2(va.y, vb.y);
      u.z = pack_bf2(va.z, vb.z); u.w = pack_bf2(va.w, vb.w);
      *(uint4*)(in_t2 + cp * CP_STR + rr * 68 + 4 + w4 * 4) = u;
    }
  }
  __syncthreads();

  const int cp = t & 7, g = t >> 3;
  const int cgx = g % 7, rq = g / 7;           // g<28 active
  if (g < 28) {
    const float* wpA = cw + (cg * 16 + cp * 2) * 49;
    f32x2 bias2;
    bias2.x = cb[cg * 16 + cp * 2];
    bias2.y = cb[cg * 16 + cp * 2 + 1];
    const unsigned* base = in_t2 + cp * CP_STR + rq * 2 * 68 + cgx * 8;
    f32x2 acc2[2][8] = {};
    f32x2 wr2[7], wn2[7];
#pragma unroll
    for (int i = 0; i < 7; ++i) { wr2[i].x = wpA[i]; wr2[i].y = wpA[49 + i]; }
#pragma unroll
    for (int kh = 0; kh < 7; ++kh) {
      if (kh < 6) {
#pragma unroll
        for (int i = 0; i < 7; ++i) {
          wn2[i].x = wpA[(kh + 1) * 7 + i];
          wn2[i].y = wpA[49 + (kh + 1) * 7 + i];
        }
      }
      if (kh == 3) { wr2[3].x += 1.0f; wr2[3].y += 1.0f; }   // residual = center tap + 1
#pragma unroll
      for (int r = 0; r < 2; ++r) {
        const unsigned* rp = base + (r + kh) * 68;
        uint4 d0 = *(const uint4*)(rp);
        uint4 d1 = *(const uint4*)(rp + 4);
        uint4 d2 = *(const uint4*)(rp + 8);
        uint4 d3 = *(const uint4*)(rp + 12);
        unsigned dw[16] = { d0.x, d0.y, d0.z, d0.w, d1.x, d1.y, d1.z, d1.w,
                            d2.x, d2.y, d2.z, d2.w, d3.x, d3.y, d3.z, d3.w };
        f32x2 v2[16];
#pragma unroll
        for (int q = 0; q < 16; ++q) v2[q] = up2(dw[q]);
#pragma unroll
        for (int kw = 0; kw < 7; ++kw) {
#pragma unroll
          for (int ww = 0; ww < 8; ++ww)
            acc2[r][ww] = pk_fma(wr2[kw], v2[ww + kw + 1], acc2[r][ww]);
        }
      }
#pragma unroll
      for (int i = 0; i < 7; ++i) wr2[i] = wn2[i];
    }
    // BLOCKED stores: region private to this block; 8 cp-lanes = 32B line segments
    short* dst0 = (short*)y0b +
        ((size_t)(b * 12 + cg) * HW + (size_t)(h0 + rq * 2) * 56 + cgx * 8) * 16 + cp * 2;
#pragma unroll
    for (int r = 0; r < 2; ++r)
#pragma unroll
      for (int ww = 0; ww < 8; ++ww) {
        unsigned pv = pack_bf2(acc2[r][ww].x + bias2.x, acc2[r][ww].y + bias2.y);
        *(unsigned*)(dst0 + (size_t)(r * 56 + ww) * 16) = pv;
      }
  }
}

// ---------------- xj helpers (serial 5-pt gather) ----------------
__device__ __forceinline__ void xj_load(short8 (&nb)[5], const short* y1c, int hwl) {
  int h = hwl / 56, w = hwl - h * 56;
  int hp = (h >= 54) ? h - 54 : h + 2;
  int hm = (h < 2) ? h + 54 : h - 2;
  int wp = (w >= 54) ? w - 54 : w + 2;
  int wm = (w < 2) ? w + 54 : w - 2;
  nb[0] = *(const short8*)(y1c + (size_t)hwl * CC);
  nb[1] = *(const short8*)(y1c + (size_t)(hp * 56 + w) * CC);
  nb[2] = *(const short8*)(y1c + (size_t)(hm * 56 + w) * CC);
  nb[3] = *(const short8*)(y1c + (size_t)(h * 56 + wp) * CC);
  nb[4] = *(const short8*)(y1c + (size_t)(h * 56 + wm) * CC);
}
__device__ __forceinline__ void xj_write(char* dst, const short8 (&nb)[5], int dstoff) {
  short8 res;
#pragma unroll
  for (int q = 0; q < 8; ++q) {
    float m = fmaxf(fmaxf(bf2f(nb[1][q]), bf2f(nb[2][q])),
                    fmaxf(bf2f(nb[3][q]), bf2f(nb[4][q])));
    res[q] = f2bf(fmaxf(m - bf2f(nb[0][q]), 0.0f));
  }
  *(short8*)(dst + dstoff) = res;
}

// ---------------- gemm template: MODE 0 (blocked y0 in, bf16 pm out) / MODE 2 (pm in, f32 cm out) ----------------
template<int MODE>
__global__ void __launch_bounds__(256, 2) gemm_kernel(
    const __hip_bfloat16* __restrict__ actA,
    const __hip_bfloat16* __restrict__ Wf, const float* __restrict__ bfv,
    void* __restrict__ outp) {
  __shared__ char smem[2][24576];
  const int t = threadIdx.x;
  const int lane = t & 63, w = t >> 6;
  const int lrow = lane & 15, lhi = lane >> 4;
  constexpr int NT = NB * 49;          // 1568 pixel tiles of 64

  // per-thread source offsets for 6 gl_lds transfers (LDS layout identical in both modes)
  int goff[6];
#pragma unroll
  for (int j = 0; j < 6; ++j) {
    int idx = j * 4096 + t * 16;
    int p = idx / 384, qd = idx - p * 384;
    int q2 = qd ^ ((p & 7) << 4);
    if (MODE == 0)
      goff[j] = (q2 >> 5) * (HW * 32) + p * 32 + (q2 & 31);   // blocked [cg][px][16ch]
    else
      goff[j] = p * 384 + q2;                                 // pixel-major
  }

  float bw0[3];
  float bw2[3][4];
  if (MODE != 2) {
#pragma unroll
    for (int wi = 0; wi < 3; ++wi) bw0[wi] = bfv[w * 48 + wi * 16 + lrow];
  } else {
#pragma unroll
    for (int wi = 0; wi < 3; ++wi)
#pragma unroll
      for (int r = 0; r < 4; ++r) bw2[wi][r] = bfv[w * 48 + wi * 16 + lhi * 4 + r];
  }

  short8 wreg[6][3];
#pragma unroll
  for (int kk = 0; kk < 6; ++kk)
#pragma unroll
    for (int wi = 0; wi < 3; ++wi) {
      int o = w * 48 + wi * 16 + lrow;
      wreg[kk][wi] = *(const short8*)((const short*)Wf + (size_t)o * 192 + kk * 32 + lhi * 8);
    }

  auto tbase = [&](int tl) -> size_t {
    if (MODE == 0) {
      int bi = tl / 49;
      return (size_t)bi * (CC * HW * 2) + (size_t)(tl - bi * 49) * 64 * 32;
    }
    return (size_t)tl * 24576;
  };

  const int step = gridDim.x;
  int tile = blockIdx.x;
  {
    const char* src = (const char*)actA + tbase(tile);
#pragma unroll
    for (int j = 0; j < 6; ++j)
      gl2lds(src + goff[j], smem[0] + j * 4096 + w * 1024);
  }
  __syncthreads();
  int cur = 0;

  while (tile < NT) {
    const int tnext = tile + step;
    f32x4 acc[4][3] = {};
    if (tnext < NT) {
      const char* nsrc = (const char*)actA + tbase(tnext);
#pragma unroll
      for (int j = 0; j < 6; ++j)
        gl2lds(nsrc + goff[j], smem[cur ^ 1] + j * 4096 + w * 1024);
    }
#pragma unroll
    for (int kk = 0; kk < 6; ++kk) {
      short8 af[4];
#pragma unroll
      for (int ai = 0; ai < 4; ++ai) {
        int p = ai * 16 + lrow;
        af[ai] = *(const short8*)(smem[cur] + p * 384 + ((kk * 64 + lhi * 16) ^ ((p & 7) << 4)));
      }
#pragma unroll
      for (int ai = 0; ai < 4; ++ai)
#pragma unroll
        for (int wi = 0; wi < 3; ++wi)
          acc[ai][wi] = (MODE == 2)
              ? __builtin_amdgcn_mfma_f32_16x16x32_bf16(wreg[kk][wi], af[ai], acc[ai][wi], 0, 0, 0)
              : __builtin_amdgcn_mfma_f32_16x16x32_bf16(af[ai], wreg[kk][wi], acc[ai][wi], 0, 0, 0);
    }
    __syncthreads();
    cur ^= 1;

    if (MODE != 2) {
      short* ob = (short*)outp + (size_t)tile * 64 * CC;
#pragma unroll
      for (int wi = 0; wi < 3; ++wi) {
        int o = w * 48 + wi * 16 + lrow;
#pragma unroll
        for (int ai = 0; ai < 4; ++ai)
#pragma unroll
          for (int r = 0; r < 4; ++r) {
            int p = ai * 16 + lhi * 4 + r;
            ob[(size_t)p * CC + o] = f2bf(acc[ai][wi][r] + bw0[wi]);
          }
      }
    } else {
      int bimg = tile / 49, hwbase = (tile - bimg * 49) * 64;
      float* ob = (float*)outp + (size_t)bimg * CC * HW + hwbase;
#pragma unroll
      for (int wi = 0; wi < 3; ++wi)
#pragma unroll
        for (int r = 0; r < 4; ++r) {
          int o = w * 48 + wi * 16 + lhi * 4 + r;
#pragma unroll
          for (int ai = 0; ai < 4; ++ai)
            ob[(size_t)o * HW + ai * 16 + lrow] = acc[ai][wi][r] + bw2[wi][r];
        }
    }
    tile = tnext;
  }
}

// ---------------- gemm2: 768 threads = 12 waves x 16-o slice, T14-split fused xj, GELU ----------------
__global__ void __launch_bounds__(768, 3) gemm2_kernel(
    const __hip_bfloat16* __restrict__ y1g, const __hip_bfloat16* __restrict__ Wf,
    const float* __restrict__ bfv, __hip_bfloat16* __restrict__ outp) {
  __shared__ char smem[2][24576];
  const int t = threadIdx.x;
  const int lane = t & 63, w = t >> 6;        // w in 0..11
  const int lrow = lane & 15, lhi = lane >> 4;
  constexpr int NT = NB * 49;

  int sp[2], sq[2], goff[2];
#pragma unroll
  for (int j = 0; j < 2; ++j) {
    int idx = j * 12288 + t * 16;
    sp[j] = idx / 384;
    sq[j] = idx - sp[j] * 384;
    goff[j] = sp[j] * 384 + (sq[j] ^ ((sp[j] & 7) << 4));
  }

  const float bw = bfv[w * 16 + lrow];

  short8 wreg[2][6];
#pragma unroll
  for (int c = 0; c < 2; ++c)
#pragma unroll
    for (int kk = 0; kk < 6; ++kk) {
      int o = w * 16 + lrow;
      wreg[c][kk] = *(const short8*)((const short*)Wf +
          (size_t)o * 384 + c * 192 + kk * 32 + lhi * 8);
    }

  const int step = gridDim.x;
  int tile = blockIdx.x;
  {
    const char* src = (const char*)y1g + (size_t)tile * 24576;
#pragma unroll
    for (int j = 0; j < 2; ++j)
      gl2lds(src + goff[j], smem[0] + j * 12288 + w * 1024);
  }
  __syncthreads();
  int cur = 0;

  while (tile < NT) {
    const int tnext = tile + step;
    const int bimg = tile / 49;
    const int hwbase = (tile - bimg * 49) * 64;
    const short* y1b = (const short*)y1g + (size_t)bimg * HW * CC;
    f32x4 acc[4] = {};

    // ---- c = 0: ISSUE xj gathers early (regs), MFMA chunk 0, THEN finish xj (T14 split) ----
    short8 nbA[5], nbB[5];
    xj_load(nbA, y1b + (sq[0] >> 1), hwbase + sp[0]);
    xj_load(nbB, y1b + (sq[1] >> 1), hwbase + sp[1]);
#pragma unroll
    for (int kk = 0; kk < 6; ++kk) {
      short8 af[4];
#pragma unroll
      for (int ai = 0; ai < 4; ++ai) {
        int p = ai * 16 + lrow;
        af[ai] = *(const short8*)(smem[cur] + p * 384 + ((kk * 64 + lhi * 16) ^ ((p & 7) << 4)));
      }
#pragma unroll
      for (int ai = 0; ai < 4; ++ai)
        acc[ai] = __builtin_amdgcn_mfma_f32_16x16x32_bf16(af[ai], wreg[0][kk], acc[ai], 0, 0, 0);
    }
    // gather latency has been covered by the MFMA phase; now unpack/max/write
    xj_write(smem[cur ^ 1], nbA, goff[0]);
    xj_write(smem[cur ^ 1], nbB, goff[1]);
    __syncthreads();
    cur ^= 1;

    // ---- c = 1: stage next tile's chunk 0 via gl_lds; compute chunk 1 (xj) ----
    if (tnext < NT) {
      const char* nsrc = (const char*)y1g + (size_t)tnext * 24576;
#pragma unroll
      for (int j = 0; j < 2; ++j)
        gl2lds(nsrc + goff[j], smem[cur ^ 1] + j * 12288 + w * 1024);
    }
#pragma unroll
    for (int kk = 0; kk < 6; ++kk) {
      short8 af[4];
#pragma unroll
      for (int ai = 0; ai < 4; ++ai) {
        int p = ai * 16 + lrow;
        af[ai] = *(const short8*)(smem[cur] + p * 384 + ((kk * 64 + lhi * 16) ^ ((p & 7) << 4)));
      }
#pragma unroll
      for (int ai = 0; ai < 4; ++ai)
        acc[ai] = __builtin_amdgcn_mfma_f32_16x16x32_bf16(af[ai], wreg[1][kk], acc[ai], 0, 0, 0);
    }
    __syncthreads();
    cur ^= 1;

    // ---- epilogue: bias + tanh-GELU -> y2 bf16 pixel-major ----
    short* ob = (short*)outp + (size_t)tile * 64 * CC;
    const int o = w * 16 + lrow;
#pragma unroll
    for (int ai = 0; ai < 4; ++ai)
#pragma unroll
      for (int r = 0; r < 4; ++r) {
        int p = ai * 16 + lhi * 4 + r;
        ob[(size_t)p * CC + o] = f2bf(geluf(acc[ai][r] + bw));
      }
    tile = tnext;
  }
}

extern "C" void kernel_launch(void* const* d_in, const int* in_sizes, int n_in,
                              void* d_out, int out_size, void* d_ws, size_t ws_size,
                              hipStream_t stream) {
  const float* x     = (const float*)d_in[0];
  const float* cpe_w = (const float*)d_in[1];
  const float* cpe_b = (const float*)d_in[2];
  const float* fc1_w = (const float*)d_in[3];
  const float* fc1_b = (const float*)d_in[4];
  const float* bn1_g = (const float*)d_in[5];
  const float* bn1_b = (const float*)d_in[6];
  const float* bn1_m = (const float*)d_in[7];
  const float* bn1_v = (const float*)d_in[8];
  const float* gc_w  = (const float*)d_in[9];
  const float* gc_b  = (const float*)d_in[10];
  const float* bng_g = (const float*)d_in[11];
  const float* bng_b = (const float*)d_in[12];
  const float* bng_m = (const float*)d_in[13];
  const float* bng_v = (const float*)d_in[14];
  const float* fc2_w = (const float*)d_in[15];
  const float* fc2_b = (const float*)d_in[16];
  const float* bn2_g = (const float*)d_in[17];
  const float* bn2_b = (const float*)d_in[18];
  const float* bn2_m = (const float*)d_in[19];
  const float* bn2_v = (const float*)d_in[20];

  if (ws_size < 77594624) return;
  char* ws = (char*)d_ws;
  __hip_bfloat16* W1f = (__hip_bfloat16*)(ws);
  __hip_bfloat16* Wgf = (__hip_bfloat16*)(ws + 73728);
  __hip_bfloat16* W2f = (__hip_bfloat16*)(ws + 221184);
  float* b1f = (float*)(ws + 294912);
  float* bgf = (float*)(ws + 295680);
  float* b2f = (float*)(ws + 296448);
  __hip_bfloat16* y0  = (__hip_bfloat16*)(ws + 524288);       // blocked for dwconv->gemm1; reused pm as y2
  __hip_bfloat16* y1  = (__hip_bfloat16*)d_out;               // d_out as bf16 scratch
  float* out = (float*)d_out;

  fold_kernel<<<576, 256, 0, stream>>>(fc1_w, fc1_b, bn1_g, bn1_b, bn1_m, bn1_v,
      gc_w, gc_b, bng_g, bng_b, bng_m, bng_v, fc2_w, fc2_b, bn2_g, bn2_b, bn2_m, bn2_v,
      W1f, Wgf, W2f, b1f, bgf, b2f);
  dwconv_kernel<<<NB * 12 * 7, 256, 0, stream>>>(x, cpe_w, cpe_b, y0);
  gemm_kernel<0><<<512, 256, 0, stream>>>(y0, W1f, b1f, y1);
  gemm2_kernel<<<512, 768, 0, stream>>>(y1, Wgf, bgf, y0);
  gemm_kernel<2><<<512, 256, 0, stream>>>(y0, W2f, b2f, out);
}

// Round 24
// 141.535 us; speedup vs baseline: 1.1557x; 1.1557x over previous
//
#include <hip/hip_runtime.h>
#include <hip/hip_bf16.h>

// Grapher block: RepCPE(dw7x7+res) -> fc1+BN -> MRConv4d(K=2) -> gc(2C->C)+BN+GELU -> fc2+BN
// B=32, C=192, H=W=56. d_in/d_out FLOAT32; intermediates bf16.
//
//   fold:   BN-fold weights -> W1f[192][192], Wgf[192][384], W2f[192][192] (bf16), biases fp32
//   dwconv: v13 = v10 (pm layout, 4/CU) + BATCHED staging: issue all 14 float4 loads into
//           regs, THEN pack+ds_write (covers HBM latency; was ~2 outstanding loads/thread)
//   gemm1:  template MODE 0 (256 thr) -> y1 bf16 pm (d_out scratch)
//   gemm2:  768-thread, T14-split fused xj, tanh-GELU -> y2 bf16 pm
//   gemm3:  template MODE 2 (256 thr, swapped ops) -> d_out f32 channel-major

#define CC   192
#define HW   3136
#define NB   32
#define CP_STR 957                             // dwords; -3 mod 32 (bank-conflict-free)

using short8 = __attribute__((ext_vector_type(8))) short;
using f32x4  = __attribute__((ext_vector_type(4))) float;
using f32x2  = __attribute__((ext_vector_type(2))) float;

__device__ __forceinline__ float bf2f(short s) {
  union { unsigned u; float f; } x; x.u = ((unsigned)(unsigned short)s) << 16; return x.f;
}
__device__ __forceinline__ short f2bf(float f) {
  __hip_bfloat16 h = __float2bfloat16(f);
  return *reinterpret_cast<short*>(&h);
}
__device__ __forceinline__ unsigned pack_bf2(float a, float b) {
  return ((unsigned)(unsigned short)f2bf(a)) | (((unsigned)(unsigned short)f2bf(b)) << 16);
}
__device__ __forceinline__ f32x2 up2(unsigned d) {
  union { unsigned u; float f; } lo, hi;
  lo.u = d << 16; hi.u = d & 0xffff0000u;
  f32x2 r; r.x = lo.f; r.y = hi.f; return r;
}
// packed dual-FP32 FMA: d = a*b + c elementwise on 2 floats (one instruction)
__device__ __forceinline__ f32x2 pk_fma(f32x2 a, f32x2 b, f32x2 c) {
  f32x2 d;
  asm("v_pk_fma_f32 %0, %1, %2, %3" : "=v"(d) : "v"(a), "v"(b), "v"(c));
  return d;
}
// tanh-form GELU: max |delta| vs erf-form ~1e-3 (<< 0.08 tol). Inf-safe: 2 - 2/(e+1).
__device__ __forceinline__ float geluf(float v) {
  float u = 0.7978845608028654f * (v + 0.044715f * v * v * v);
  float e = __expf(2.0f * u);
  return 0.5f * v * (2.0f - 2.0f / (e + 1.0f));
}
__device__ __forceinline__ void gl2lds(const char* g, char* l) {
  __builtin_amdgcn_global_load_lds(
      (const __attribute__((address_space(1))) void*)g,
      (__attribute__((address_space(3))) void*)l, 16, 0, 0);
}

// ---------------- fold: BN into weights/bias ----------------
__global__ void __launch_bounds__(256) fold_kernel(
    const float* __restrict__ fc1_w, const float* __restrict__ fc1_b,
    const float* __restrict__ bn1_g, const float* __restrict__ bn1_b,
    const float* __restrict__ bn1_m, const float* __restrict__ bn1_v,
    const float* __restrict__ gc_w,  const float* __restrict__ gc_b,
    const float* __restrict__ bng_g, const float* __restrict__ bng_b,
    const float* __restrict__ bng_m, const float* __restrict__ bng_v,
    const float* __restrict__ fc2_w, const float* __restrict__ fc2_b,
    const float* __restrict__ bn2_g, const float* __restrict__ bn2_b,
    const float* __restrict__ bn2_m, const float* __restrict__ bn2_v,
    __hip_bfloat16* __restrict__ W1f, __hip_bfloat16* __restrict__ Wgf, __hip_bfloat16* __restrict__ W2f,
    float* __restrict__ b1f, float* __restrict__ bgf, float* __restrict__ b2f) {
  int gt = blockIdx.x * 256 + threadIdx.x;
  if (gt < 3 * CC) {
    int which = gt / CC, o = gt - which * CC;
    const float *G, *Bt, *M, *V, *Bi; float* dst;
    if (which == 0)      { G = bn1_g; Bt = bn1_b; M = bn1_m; V = bn1_v; Bi = fc1_b; dst = b1f; }
    else if (which == 1) { G = bng_g; Bt = bng_b; M = bng_m; V = bng_v; Bi = gc_b;  dst = bgf; }
    else                 { G = bn2_g; Bt = bn2_b; M = bn2_m; V = bn2_v; Bi = fc2_b; dst = b2f; }
    float inv = G[o] * rsqrtf(V[o] + 1e-5f);
    dst[o] = Bi[o] * inv + Bt[o] - M[o] * inv;
  }
  int i = gt;
  if (i < CC * CC) {
    int o = i / CC;
    float inv = bn1_g[o] * rsqrtf(bn1_v[o] + 1e-5f);
    W1f[i] = __float2bfloat16(fc1_w[i] * inv);
  } else if (i < CC * CC + CC * 2 * CC) {
    int j = i - CC * CC; int o = j / (2 * CC);
    float inv = bng_g[o] * rsqrtf(bng_v[o] + 1e-5f);
    Wgf[j] = __float2bfloat16(gc_w[j] * inv);
  } else if (i < CC * CC * 4) {
    int j = i - CC * CC * 3; int o = j / CC;
    float inv = bn2_g[o] * rsqrtf(bn2_v[o] + 1e-5f);
    W2f[j] = __float2bfloat16(fc2_w[j] * inv);
  }
}

// ---------------- dw 7x7 + bias + residual -> PIXEL-MAJOR bf16 (v13) ----------------
// v10 + batched staging: all 14 float4 loads issued before pack/ds_write.
__global__ void __launch_bounds__(256, 4) dwconv_kernel(
    const float* __restrict__ x, const float* __restrict__ cw,
    const float* __restrict__ cb, __hip_bfloat16* __restrict__ y0pm) {
  __shared__ unsigned in_t2[8 * CP_STR];       // 30624 B
  const int t = threadIdx.x;
  int bb = blockIdx.x;
  const int rs = bb % 7;  bb /= 7;
  const int cg = bb % 12; bb /= 12;
  const int b  = bb;
  const int h0 = rs * 8;

  for (int i = t; i < 8 * CP_STR / 4; i += 256) ((uint4*)in_t2)[i] = uint4{0, 0, 0, 0};
  __syncthreads();

  // BATCHED staging: rows h0-3 .. h0+10 (14 rows), 8 channel-pairs, packed bf16x2.
  // Phase 1: issue all loads into regs; Phase 2: pack + ds_write.
  {
    float4 va[7], vb[7];
    bool vld[7];
    int dsto[7];
#pragma unroll
    for (int ii = 0; ii < 7; ++ii) {
      int it = t + ii * 256;
      bool act = it < 8 * 14 * 14;
      int w4 = it % 14, rr = (it / 14) % 14, cp = it / 196;
      int gh = h0 - 3 + rr;
      vld[ii] = act && gh >= 0 && gh < 56;
      dsto[ii] = cp * CP_STR + rr * 68 + 4 + w4 * 4;
      if (vld[ii]) {
        const float* pa = x + ((size_t)(b * CC + cg * 16 + cp * 2) * 56 + gh) * 56 + w4 * 4;
        va[ii] = *(const float4*)pa;
        vb[ii] = *(const float4*)(pa + 3136);  // next channel (56*56)
      }
    }
#pragma unroll
    for (int ii = 0; ii < 7; ++ii) {
      if (vld[ii]) {
        uint4 u;
        u.x = pack_bf2(va[ii].x, vb[ii].x); u.y = pack_bf2(va[ii].y, vb[ii].y);
        u.z = pack_bf2(va[ii].z, vb[ii].z); u.w = pack_bf2(va[ii].w, vb[ii].w);
        *(uint4*)(in_t2 + dsto[ii]) = u;
      }
    }
  }
  __syncthreads();

  const int cp = t & 7, g = t >> 3;
  const int cgx = g % 7, rq = g / 7;           // g<28 active
  if (g < 28) {
    const float* wpA = cw + (cg * 16 + cp * 2) * 49;
    f32x2 bias2;
    bias2.x = cb[cg * 16 + cp * 2];
    bias2.y = cb[cg * 16 + cp * 2 + 1];
    const unsigned* base = in_t2 + cp * CP_STR + rq * 2 * 68 + cgx * 8;
    f32x2 acc2[2][8] = {};
    f32x2 wr2[7], wn2[7];
#pragma unroll
    for (int i = 0; i < 7; ++i) { wr2[i].x = wpA[i]; wr2[i].y = wpA[49 + i]; }
#pragma unroll
    for (int kh = 0; kh < 7; ++kh) {
      if (kh < 6) {
#pragma unroll
        for (int i = 0; i < 7; ++i) {
          wn2[i].x = wpA[(kh + 1) * 7 + i];
          wn2[i].y = wpA[49 + (kh + 1) * 7 + i];
        }
      }
      if (kh == 3) { wr2[3].x += 1.0f; wr2[3].y += 1.0f; }   // residual = center tap + 1
#pragma unroll
      for (int r = 0; r < 2; ++r) {
        const unsigned* rp = base + (r + kh) * 68;
        uint4 d0 = *(const uint4*)(rp);
        uint4 d1 = *(const uint4*)(rp + 4);
        uint4 d2 = *(const uint4*)(rp + 8);
        uint4 d3 = *(const uint4*)(rp + 12);
        unsigned dw[16] = { d0.x, d0.y, d0.z, d0.w, d1.x, d1.y, d1.z, d1.w,
                            d2.x, d2.y, d2.z, d2.w, d3.x, d3.y, d3.z, d3.w };
        f32x2 v2[16];
#pragma unroll
        for (int q = 0; q < 16; ++q) v2[q] = up2(dw[q]);
#pragma unroll
        for (int kw = 0; kw < 7; ++kw) {
#pragma unroll
          for (int ww = 0; ww < 8; ++ww)
            acc2[r][ww] = pk_fma(wr2[kw], v2[ww + kw + 1], acc2[r][ww]);
        }
      }
#pragma unroll
      for (int i = 0; i < 7; ++i) wr2[i] = wn2[i];
    }
    // stores: one dword = both channels; 8 cp-lanes form 32B chunks
    short* dst0 = (short*)y0pm + ((size_t)b * HW + (size_t)(h0 + rq * 2) * 56 + cgx * 8) * CC
                  + cg * 16 + cp * 2;
#pragma unroll
    for (int r = 0; r < 2; ++r)
#pragma unroll
      for (int ww = 0; ww < 8; ++ww) {
        unsigned pv = pack_bf2(acc2[r][ww].x + bias2.x, acc2[r][ww].y + bias2.y);
        *(unsigned*)(dst0 + (size_t)(r * 56 + ww) * CC) = pv;
      }
  }
}

// ---------------- xj helpers (serial 5-pt gather) ----------------
__device__ __forceinline__ void xj_load(short8 (&nb)[5], const short* y1c, int hwl) {
  int h = hwl / 56, w = hwl - h * 56;
  int hp = (h >= 54) ? h - 54 : h + 2;
  int hm = (h < 2) ? h + 54 : h - 2;
  int wp = (w >= 54) ? w - 54 : w + 2;
  int wm = (w < 2) ? w + 54 : w - 2;
  nb[0] = *(const short8*)(y1c + (size_t)hwl * CC);
  nb[1] = *(const short8*)(y1c + (size_t)(hp * 56 + w) * CC);
  nb[2] = *(const short8*)(y1c + (size_t)(hm * 56 + w) * CC);
  nb[3] = *(const short8*)(y1c + (size_t)(h * 56 + wp) * CC);
  nb[4] = *(const short8*)(y1c + (size_t)(h * 56 + wm) * CC);
}
__device__ __forceinline__ void xj_write(char* dst, const short8 (&nb)[5], int dstoff) {
  short8 res;
#pragma unroll
  for (int q = 0; q < 8; ++q) {
    float m = fmaxf(fmaxf(bf2f(nb[1][q]), bf2f(nb[2][q])),
                    fmaxf(bf2f(nb[3][q]), bf2f(nb[4][q])));
    res[q] = f2bf(fmaxf(m - bf2f(nb[0][q]), 0.0f));
  }
  *(short8*)(dst + dstoff) = res;
}

// ---------------- gemm template: MODE 0 (bf16 pm) / MODE 2 (f32 channel-major, swapped) ----------------
template<int MODE>
__global__ void __launch_bounds__(256, 2) gemm_kernel(
    const __hip_bfloat16* __restrict__ actA,
    const __hip_bfloat16* __restrict__ Wf, const float* __restrict__ bfv,
    void* __restrict__ outp) {
  __shared__ char smem[2][24576];
  const int t = threadIdx.x;
  const int lane = t & 63, w = t >> 6;
  const int lrow = lane & 15, lhi = lane >> 4;
  constexpr int NT = NB * 49;          // 1568 pixel tiles of 64

  int goff[6];
#pragma unroll
  for (int j = 0; j < 6; ++j) {
    int idx = j * 4096 + t * 16;
    int p = idx / 384, qd = idx - p * 384;
    goff[j] = p * 384 + (qd ^ ((p & 7) << 4));
  }

  float bw0[3];
  float bw2[3][4];
  if (MODE != 2) {
#pragma unroll
    for (int wi = 0; wi < 3; ++wi) bw0[wi] = bfv[w * 48 + wi * 16 + lrow];
  } else {
#pragma unroll
    for (int wi = 0; wi < 3; ++wi)
#pragma unroll
      for (int r = 0; r < 4; ++r) bw2[wi][r] = bfv[w * 48 + wi * 16 + lhi * 4 + r];
  }

  short8 wreg[6][3];
#pragma unroll
  for (int kk = 0; kk < 6; ++kk)
#pragma unroll
    for (int wi = 0; wi < 3; ++wi) {
      int o = w * 48 + wi * 16 + lrow;
      wreg[kk][wi] = *(const short8*)((const short*)Wf + (size_t)o * 192 + kk * 32 + lhi * 8);
    }

  const int step = gridDim.x;
  int tile = blockIdx.x;
  {
    const char* src = (const char*)actA + (size_t)tile * 24576;
#pragma unroll
    for (int j = 0; j < 6; ++j)
      gl2lds(src + goff[j], smem[0] + j * 4096 + w * 1024);
  }
  __syncthreads();
  int cur = 0;

  while (tile < NT) {
    const int tnext = tile + step;
    f32x4 acc[4][3] = {};
    if (tnext < NT) {
      const char* nsrc = (const char*)actA + (size_t)tnext * 24576;
#pragma unroll
      for (int j = 0; j < 6; ++j)
        gl2lds(nsrc + goff[j], smem[cur ^ 1] + j * 4096 + w * 1024);
    }
#pragma unroll
    for (int kk = 0; kk < 6; ++kk) {
      short8 af[4];
#pragma unroll
      for (int ai = 0; ai < 4; ++ai) {
        int p = ai * 16 + lrow;
        af[ai] = *(const short8*)(smem[cur] + p * 384 + ((kk * 64 + lhi * 16) ^ ((p & 7) << 4)));
      }
#pragma unroll
      for (int ai = 0; ai < 4; ++ai)
#pragma unroll
        for (int wi = 0; wi < 3; ++wi)
          acc[ai][wi] = (MODE == 2)
              ? __builtin_amdgcn_mfma_f32_16x16x32_bf16(wreg[kk][wi], af[ai], acc[ai][wi], 0, 0, 0)
              : __builtin_amdgcn_mfma_f32_16x16x32_bf16(af[ai], wreg[kk][wi], acc[ai][wi], 0, 0, 0);
    }
    __syncthreads();
    cur ^= 1;

    if (MODE != 2) {
      short* ob = (short*)outp + (size_t)tile * 64 * CC;
#pragma unroll
      for (int wi = 0; wi < 3; ++wi) {
        int o = w * 48 + wi * 16 + lrow;
#pragma unroll
        for (int ai = 0; ai < 4; ++ai)
#pragma unroll
          for (int r = 0; r < 4; ++r) {
            int p = ai * 16 + lhi * 4 + r;
            ob[(size_t)p * CC + o] = f2bf(acc[ai][wi][r] + bw0[wi]);
          }
      }
    } else {
      int bimg = tile / 49, hwbase = (tile - bimg * 49) * 64;
      float* ob = (float*)outp + (size_t)bimg * CC * HW + hwbase;
#pragma unroll
      for (int wi = 0; wi < 3; ++wi)
#pragma unroll
        for (int r = 0; r < 4; ++r) {
          int o = w * 48 + wi * 16 + lhi * 4 + r;
#pragma unroll
          for (int ai = 0; ai < 4; ++ai)
            ob[(size_t)o * HW + ai * 16 + lrow] = acc[ai][wi][r] + bw2[wi][r];
        }
    }
    tile = tnext;
  }
}

// ---------------- gemm2: 768 threads = 12 waves x 16-o slice, T14-split fused xj, GELU ----------------
__global__ void __launch_bounds__(768, 3) gemm2_kernel(
    const __hip_bfloat16* __restrict__ y1g, const __hip_bfloat16* __restrict__ Wf,
    const float* __restrict__ bfv, __hip_bfloat16* __restrict__ outp) {
  __shared__ char smem[2][24576];
  const int t = threadIdx.x;
  const int lane = t & 63, w = t >> 6;        // w in 0..11
  const int lrow = lane & 15, lhi = lane >> 4;
  constexpr int NT = NB * 49;

  int sp[2], sq[2], goff[2];
#pragma unroll
  for (int j = 0; j < 2; ++j) {
    int idx = j * 12288 + t * 16;
    sp[j] = idx / 384;
    sq[j] = idx - sp[j] * 384;
    goff[j] = sp[j] * 384 + (sq[j] ^ ((sp[j] & 7) << 4));
  }

  const float bw = bfv[w * 16 + lrow];

  short8 wreg[2][6];
#pragma unroll
  for (int c = 0; c < 2; ++c)
#pragma unroll
    for (int kk = 0; kk < 6; ++kk) {
      int o = w * 16 + lrow;
      wreg[c][kk] = *(const short8*)((const short*)Wf +
          (size_t)o * 384 + c * 192 + kk * 32 + lhi * 8);
    }

  const int step = gridDim.x;
  int tile = blockIdx.x;
  {
    const char* src = (const char*)y1g + (size_t)tile * 24576;
#pragma unroll
    for (int j = 0; j < 2; ++j)
      gl2lds(src + goff[j], smem[0] + j * 12288 + w * 1024);
  }
  __syncthreads();
  int cur = 0;

  while (tile < NT) {
    const int tnext = tile + step;
    const int bimg = tile / 49;
    const int hwbase = (tile - bimg * 49) * 64;
    const short* y1b = (const short*)y1g + (size_t)bimg * HW * CC;
    f32x4 acc[4] = {};

    // ---- c = 0: ISSUE xj gathers early (regs), MFMA chunk 0, THEN finish xj (T14 split) ----
    short8 nbA[5], nbB[5];
    xj_load(nbA, y1b + (sq[0] >> 1), hwbase + sp[0]);
    xj_load(nbB, y1b + (sq[1] >> 1), hwbase + sp[1]);
#pragma unroll
    for (int kk = 0; kk < 6; ++kk) {
      short8 af[4];
#pragma unroll
      for (int ai = 0; ai < 4; ++ai) {
        int p = ai * 16 + lrow;
        af[ai] = *(const short8*)(smem[cur] + p * 384 + ((kk * 64 + lhi * 16) ^ ((p & 7) << 4)));
      }
#pragma unroll
      for (int ai = 0; ai < 4; ++ai)
        acc[ai] = __builtin_amdgcn_mfma_f32_16x16x32_bf16(af[ai], wreg[0][kk], acc[ai], 0, 0, 0);
    }
    // gather latency has been covered by the MFMA phase; now unpack/max/write
    xj_write(smem[cur ^ 1], nbA, goff[0]);
    xj_write(smem[cur ^ 1], nbB, goff[1]);
    __syncthreads();
    cur ^= 1;

    // ---- c = 1: stage next tile's chunk 0 via gl_lds; compute chunk 1 (xj) ----
    if (tnext < NT) {
      const char* nsrc = (const char*)y1g + (size_t)tnext * 24576;
#pragma unroll
      for (int j = 0; j < 2; ++j)
        gl2lds(nsrc + goff[j], smem[cur ^ 1] + j * 12288 + w * 1024);
    }
#pragma unroll
    for (int kk = 0; kk < 6; ++kk) {
      short8 af[4];
#pragma unroll
      for (int ai = 0; ai < 4; ++ai) {
        int p = ai * 16 + lrow;
        af[ai] = *(const short8*)(smem[cur] + p * 384 + ((kk * 64 + lhi * 16) ^ ((p & 7) << 4)));
      }
#pragma unroll
      for (int ai = 0; ai < 4; ++ai)
        acc[ai] = __builtin_amdgcn_mfma_f32_16x16x32_bf16(af[ai], wreg[1][kk], acc[ai], 0, 0, 0);
    }
    __syncthreads();
    cur ^= 1;

    // ---- epilogue: bias + tanh-GELU -> y2 bf16 pixel-major ----
    short* ob = (short*)outp + (size_t)tile * 64 * CC;
    const int o = w * 16 + lrow;
#pragma unroll
    for (int ai = 0; ai < 4; ++ai)
#pragma unroll
      for (int r = 0; r < 4; ++r) {
        int p = ai * 16 + lhi * 4 + r;
        ob[(size_t)p * CC + o] = f2bf(geluf(acc[ai][r] + bw));
      }
    tile = tnext;
  }
}

extern "C" void kernel_launch(void* const* d_in, const int* in_sizes, int n_in,
                              void* d_out, int out_size, void* d_ws, size_t ws_size,
                              hipStream_t stream) {
  const float* x     = (const float*)d_in[0];
  const float* cpe_w = (const float*)d_in[1];
  const float* cpe_b = (const float*)d_in[2];
  const float* fc1_w = (const float*)d_in[3];
  const float* fc1_b = (const float*)d_in[4];
  const float* bn1_g = (const float*)d_in[5];
  const float* bn1_b = (const float*)d_in[6];
  const float* bn1_m = (const float*)d_in[7];
  const float* bn1_v = (const float*)d_in[8];
  const float* gc_w  = (const float*)d_in[9];
  const float* gc_b  = (const float*)d_in[10];
  const float* bng_g = (const float*)d_in[11];
  const float* bng_b = (const float*)d_in[12];
  const float* bng_m = (const float*)d_in[13];
  const float* bng_v = (const float*)d_in[14];
  const float* fc2_w = (const float*)d_in[15];
  const float* fc2_b = (const float*)d_in[16];
  const float* bn2_g = (const float*)d_in[17];
  const float* bn2_b = (const float*)d_in[18];
  const float* bn2_m = (const float*)d_in[19];
  const float* bn2_v = (const float*)d_in[20];

  if (ws_size < 77594624) return;
  char* ws = (char*)d_ws;
  __hip_bfloat16* W1f = (__hip_bfloat16*)(ws);
  __hip_bfloat16* Wgf = (__hip_bfloat16*)(ws + 73728);
  __hip_bfloat16* W2f = (__hip_bfloat16*)(ws + 221184);
  float* b1f = (float*)(ws + 294912);
  float* bgf = (float*)(ws + 295680);
  float* b2f = (float*)(ws + 296448);
  __hip_bfloat16* y0  = (__hip_bfloat16*)(ws + 524288);       // pixel-major; reused as y2
  __hip_bfloat16* y1  = (__hip_bfloat16*)d_out;               // d_out as bf16 scratch
  float* out = (float*)d_out;

  fold_kernel<<<576, 256, 0, stream>>>(fc1_w, fc1_b, bn1_g, bn1_b, bn1_m, bn1_v,
      gc_w, gc_b, bng_g, bng_b, bng_m, bng_v, fc2_w, fc2_b, bn2_g, bn2_b, bn2_m, bn2_v,
      W1f, Wgf, W2f, b1f, bgf, b2f);
  dwconv_kernel<<<NB * 12 * 7, 256, 0, stream>>>(x, cpe_w, cpe_b, y0);
  gemm_kernel<0><<<512, 256, 0, stream>>>(y0, W1f, b1f, y1);
  gemm2_kernel<<<512, 768, 0, stream>>>(y1, Wgf, bgf, y0);
  gemm_kernel<2><<<512, 256, 0, stream>>>(y0, W2f, b2f, out);
}

// Round 25
// 138.220 us; speedup vs baseline: 1.1834x; 1.0240x over previous
//
#include <hip/hip_runtime.h>
#include <hip/hip_bf16.h>
#include <hip/hip_fp16.h>

// Grapher block: RepCPE(dw7x7+res) -> fc1+BN -> MRConv4d(K=2) -> gc(2C->C)+BN+GELU -> fc2+BN
// B=32, C=192, H=W=56. d_in/d_out FLOAT32; intermediates bf16.
//
//   fold:   BN-fold weights -> W1f[192][192], Wgf[192][384], W2f[192][192] (bf16), biases fp32
//   dwconv: v15 = v10 frame with FP16-PAIR LDS + v_pk_fma_f16 (__hfma2): LDS dwords are
//           directly-consumable half2 operands -> the 448-op bf16 unpack chain vanishes.
//           fp16 accumulate (err ~2e-3 << 0.08 tol), f32 bias in epilogue.
//   gemm1:  template MODE 0 (256 thr) -> y1 bf16 pm (d_out scratch)
//   gemm2:  768-thread, T14-split fused xj, tanh-GELU -> y2 bf16 pm
//   gemm3:  template MODE 2 (256 thr, swapped ops) -> d_out f32 channel-major

#define CC   192
#define HW   3136
#define NB   32
#define CP_STR 957                             // dwords; -3 mod 32 (bank-conflict-free)

using short8 = __attribute__((ext_vector_type(8))) short;
using f32x4  = __attribute__((ext_vector_type(4))) float;

__device__ __forceinline__ float bf2f(short s) {
  union { unsigned u; float f; } x; x.u = ((unsigned)(unsigned short)s) << 16; return x.f;
}
__device__ __forceinline__ short f2bf(float f) {
  __hip_bfloat16 h = __float2bfloat16(f);
  return *reinterpret_cast<short*>(&h);
}
__device__ __forceinline__ unsigned pack_bf2(float a, float b) {
  return ((unsigned)(unsigned short)f2bf(a)) | (((unsigned)(unsigned short)f2bf(b)) << 16);
}
__device__ __forceinline__ unsigned pack_hf2(float a, float b) {
  __half2 h = __floats2half2_rn(a, b);
  union { __half2 h2; unsigned u; } c; c.h2 = h; return c.u;
}
__device__ __forceinline__ __half2 as_h2(unsigned u) {
  union { unsigned u; __half2 h2; } c; c.u = u; return c.h2;
}
// tanh-form GELU: max |delta| vs erf-form ~1e-3 (<< 0.08 tol). Inf-safe: 2 - 2/(e+1).
__device__ __forceinline__ float geluf(float v) {
  float u = 0.7978845608028654f * (v + 0.044715f * v * v * v);
  float e = __expf(2.0f * u);
  return 0.5f * v * (2.0f - 2.0f / (e + 1.0f));
}
__device__ __forceinline__ void gl2lds(const char* g, char* l) {
  __builtin_amdgcn_global_load_lds(
      (const __attribute__((address_space(1))) void*)g,
      (__attribute__((address_space(3))) void*)l, 16, 0, 0);
}

// ---------------- fold: BN into weights/bias ----------------
__global__ void __launch_bounds__(256) fold_kernel(
    const float* __restrict__ fc1_w, const float* __restrict__ fc1_b,
    const float* __restrict__ bn1_g, const float* __restrict__ bn1_b,
    const float* __restrict__ bn1_m, const float* __restrict__ bn1_v,
    const float* __restrict__ gc_w,  const float* __restrict__ gc_b,
    const float* __restrict__ bng_g, const float* __restrict__ bng_b,
    const float* __restrict__ bng_m, const float* __restrict__ bng_v,
    const float* __restrict__ fc2_w, const float* __restrict__ fc2_b,
    const float* __restrict__ bn2_g, const float* __restrict__ bn2_b,
    const float* __restrict__ bn2_m, const float* __restrict__ bn2_v,
    __hip_bfloat16* __restrict__ W1f, __hip_bfloat16* __restrict__ Wgf, __hip_bfloat16* __restrict__ W2f,
    float* __restrict__ b1f, float* __restrict__ bgf, float* __restrict__ b2f) {
  int gt = blockIdx.x * 256 + threadIdx.x;
  if (gt < 3 * CC) {
    int which = gt / CC, o = gt - which * CC;
    const float *G, *Bt, *M, *V, *Bi; float* dst;
    if (which == 0)      { G = bn1_g; Bt = bn1_b; M = bn1_m; V = bn1_v; Bi = fc1_b; dst = b1f; }
    else if (which == 1) { G = bng_g; Bt = bng_b; M = bng_m; V = bng_v; Bi = gc_b;  dst = bgf; }
    else                 { G = bn2_g; Bt = bn2_b; M = bn2_m; V = bn2_v; Bi = fc2_b; dst = b2f; }
    float inv = G[o] * rsqrtf(V[o] + 1e-5f);
    dst[o] = Bi[o] * inv + Bt[o] - M[o] * inv;
  }
  int i = gt;
  if (i < CC * CC) {
    int o = i / CC;
    float inv = bn1_g[o] * rsqrtf(bn1_v[o] + 1e-5f);
    W1f[i] = __float2bfloat16(fc1_w[i] * inv);
  } else if (i < CC * CC + CC * 2 * CC) {
    int j = i - CC * CC; int o = j / (2 * CC);
    float inv = bng_g[o] * rsqrtf(bng_v[o] + 1e-5f);
    Wgf[j] = __float2bfloat16(gc_w[j] * inv);
  } else if (i < CC * CC * 4) {
    int j = i - CC * CC * 3; int o = j / CC;
    float inv = bn2_g[o] * rsqrtf(bn2_v[o] + 1e-5f);
    W2f[j] = __float2bfloat16(fc2_w[j] * inv);
  }
}

// ---------------- dw 7x7 + bias + residual -> PIXEL-MAJOR bf16 (v15, fp16-pair hfma2) ----------------
// LDS: in_t2[8 cp][957 dw] uint (dword = fp16 chA | chB<<16). 30624 B, 4 blocks/CU.
// thread: cp = t&7, g = t>>3 (<28): cgx = g%7 owns 8 cols, rq = g/7 owns 2 rows.
// Per (kh,r): 4x b128 -> 16 half2 DIRECTLY usable -> 56 __hfma2 (no unpack at all).
__global__ void __launch_bounds__(256, 4) dwconv_kernel(
    const float* __restrict__ x, const float* __restrict__ cw,
    const float* __restrict__ cb, __hip_bfloat16* __restrict__ y0pm) {
  __shared__ unsigned in_t2[8 * CP_STR];       // 30624 B
  const int t = threadIdx.x;
  int bb = blockIdx.x;
  const int rs = bb % 7;  bb /= 7;
  const int cg = bb % 12; bb /= 12;
  const int b  = bb;
  const int h0 = rs * 8;

  for (int i = t; i < 8 * CP_STR / 4; i += 256) ((uint4*)in_t2)[i] = uint4{0, 0, 0, 0};
  __syncthreads();

  // stage rows h0-3 .. h0+10 (14 rows), 8 channel-pairs, packed fp16x2
  for (int it = t; it < 8 * 14 * 14; it += 256) {
    int w4 = it % 14, rr = (it / 14) % 14, cp = it / 196;
    int gh = h0 - 3 + rr;
    if (gh >= 0 && gh < 56) {
      const float* pa = x + ((size_t)(b * CC + cg * 16 + cp * 2) * 56 + gh) * 56 + w4 * 4;
      float4 va = *(const float4*)pa;
      float4 vb = *(const float4*)(pa + 3136);   // next channel (56*56)
      uint4 u;
      u.x = pack_hf2(va.x, vb.x); u.y = pack_hf2(va.y, vb.y);
      u.z = pack_hf2(va.z, vb.z); u.w = pack_hf2(va.w, vb.w);
      *(uint4*)(in_t2 + cp * CP_STR + rr * 68 + 4 + w4 * 4) = u;
    }
  }
  __syncthreads();

  const int cp = t & 7, g = t >> 3;
  const int cgx = g % 7, rq = g / 7;           // g<28 active
  if (g < 28) {
    const float* wpA = cw + (cg * 16 + cp * 2) * 49;
    float biasA = cb[cg * 16 + cp * 2];
    float biasB = cb[cg * 16 + cp * 2 + 1];
    const unsigned* base = in_t2 + cp * CP_STR + rq * 2 * 68 + cgx * 8;
    __half2 acc2[2][8];
    const __half2 hz = __floats2half2_rn(0.0f, 0.0f);
#pragma unroll
    for (int r = 0; r < 2; ++r)
#pragma unroll
      for (int ww = 0; ww < 8; ++ww) acc2[r][ww] = hz;

    __half2 wr2[7], wn2[7];
#pragma unroll
    for (int i = 0; i < 7; ++i) wr2[i] = __floats2half2_rn(wpA[i], wpA[49 + i]);
#pragma unroll
    for (int kh = 0; kh < 7; ++kh) {
      if (kh < 6) {
#pragma unroll
        for (int i = 0; i < 7; ++i)
          wn2[i] = __floats2half2_rn(wpA[(kh + 1) * 7 + i], wpA[49 + (kh + 1) * 7 + i]);
      }
      if (kh == 3)                              // residual = center tap + 1 (exact in f32, then cvt)
        wr2[3] = __floats2half2_rn(wpA[24] + 1.0f, wpA[73] + 1.0f);
#pragma unroll
      for (int r = 0; r < 2; ++r) {
        const unsigned* rp = base + (r + kh) * 68;
        uint4 d0 = *(const uint4*)(rp);
        uint4 d1 = *(const uint4*)(rp + 4);
        uint4 d2 = *(const uint4*)(rp + 8);
        uint4 d3 = *(const uint4*)(rp + 12);
        __half2 v2[16] = { as_h2(d0.x), as_h2(d0.y), as_h2(d0.z), as_h2(d0.w),
                           as_h2(d1.x), as_h2(d1.y), as_h2(d1.z), as_h2(d1.w),
                           as_h2(d2.x), as_h2(d2.y), as_h2(d2.z), as_h2(d2.w),
                           as_h2(d3.x), as_h2(d3.y), as_h2(d3.z), as_h2(d3.w) };
#pragma unroll
        for (int kw = 0; kw < 7; ++kw) {
#pragma unroll
          for (int ww = 0; ww < 8; ++ww)
            acc2[r][ww] = __hfma2(wr2[kw], v2[ww + kw + 1], acc2[r][ww]);
        }
      }
#pragma unroll
      for (int i = 0; i < 7; ++i) wr2[i] = wn2[i];
    }
    // stores: one dword = both channels (bf16); 8 cp-lanes form 32B chunks
    short* dst0 = (short*)y0pm + ((size_t)b * HW + (size_t)(h0 + rq * 2) * 56 + cgx * 8) * CC
                  + cg * 16 + cp * 2;
#pragma unroll
    for (int r = 0; r < 2; ++r)
#pragma unroll
      for (int ww = 0; ww < 8; ++ww) {
        float2 f = __half22float2(acc2[r][ww]);
        unsigned pv = pack_bf2(f.x + biasA, f.y + biasB);
        *(unsigned*)(dst0 + (size_t)(r * 56 + ww) * CC) = pv;
      }
  }
}

// ---------------- xj helpers (serial 5-pt gather) ----------------
__device__ __forceinline__ void xj_load(short8 (&nb)[5], const short* y1c, int hwl) {
  int h = hwl / 56, w = hwl - h * 56;
  int hp = (h >= 54) ? h - 54 : h + 2;
  int hm = (h < 2) ? h + 54 : h - 2;
  int wp = (w >= 54) ? w - 54 : w + 2;
  int wm = (w < 2) ? w + 54 : w - 2;
  nb[0] = *(const short8*)(y1c + (size_t)hwl * CC);
  nb[1] = *(const short8*)(y1c + (size_t)(hp * 56 + w) * CC);
  nb[2] = *(const short8*)(y1c + (size_t)(hm * 56 + w) * CC);
  nb[3] = *(const short8*)(y1c + (size_t)(h * 56 + wp) * CC);
  nb[4] = *(const short8*)(y1c + (size_t)(h * 56 + wm) * CC);
}
__device__ __forceinline__ void xj_write(char* dst, const short8 (&nb)[5], int dstoff) {
  short8 res;
#pragma unroll
  for (int q = 0; q < 8; ++q) {
    float m = fmaxf(fmaxf(bf2f(nb[1][q]), bf2f(nb[2][q])),
                    fmaxf(bf2f(nb[3][q]), bf2f(nb[4][q])));
    res[q] = f2bf(fmaxf(m - bf2f(nb[0][q]), 0.0f));
  }
  *(short8*)(dst + dstoff) = res;
}

// ---------------- gemm template: MODE 0 (bf16 pm) / MODE 2 (f32 channel-major, swapped) ----------------
template<int MODE>
__global__ void __launch_bounds__(256, 2) gemm_kernel(
    const __hip_bfloat16* __restrict__ actA,
    const __hip_bfloat16* __restrict__ Wf, const float* __restrict__ bfv,
    void* __restrict__ outp) {
  __shared__ char smem[2][24576];
  const int t = threadIdx.x;
  const int lane = t & 63, w = t >> 6;
  const int lrow = lane & 15, lhi = lane >> 4;
  constexpr int NT = NB * 49;          // 1568 pixel tiles of 64

  int goff[6];
#pragma unroll
  for (int j = 0; j < 6; ++j) {
    int idx = j * 4096 + t * 16;
    int p = idx / 384, qd = idx - p * 384;
    goff[j] = p * 384 + (qd ^ ((p & 7) << 4));
  }

  float bw0[3];
  float bw2[3][4];
  if (MODE != 2) {
#pragma unroll
    for (int wi = 0; wi < 3; ++wi) bw0[wi] = bfv[w * 48 + wi * 16 + lrow];
  } else {
#pragma unroll
    for (int wi = 0; wi < 3; ++wi)
#pragma unroll
      for (int r = 0; r < 4; ++r) bw2[wi][r] = bfv[w * 48 + wi * 16 + lhi * 4 + r];
  }

  short8 wreg[6][3];
#pragma unroll
  for (int kk = 0; kk < 6; ++kk)
#pragma unroll
    for (int wi = 0; wi < 3; ++wi) {
      int o = w * 48 + wi * 16 + lrow;
      wreg[kk][wi] = *(const short8*)((const short*)Wf + (size_t)o * 192 + kk * 32 + lhi * 8);
    }

  const int step = gridDim.x;
  int tile = blockIdx.x;
  {
    const char* src = (const char*)actA + (size_t)tile * 24576;
#pragma unroll
    for (int j = 0; j < 6; ++j)
      gl2lds(src + goff[j], smem[0] + j * 4096 + w * 1024);
  }
  __syncthreads();
  int cur = 0;

  while (tile < NT) {
    const int tnext = tile + step;
    f32x4 acc[4][3] = {};
    if (tnext < NT) {
      const char* nsrc = (const char*)actA + (size_t)tnext * 24576;
#pragma unroll
      for (int j = 0; j < 6; ++j)
        gl2lds(nsrc + goff[j], smem[cur ^ 1] + j * 4096 + w * 1024);
    }
#pragma unroll
    for (int kk = 0; kk < 6; ++kk) {
      short8 af[4];
#pragma unroll
      for (int ai = 0; ai < 4; ++ai) {
        int p = ai * 16 + lrow;
        af[ai] = *(const short8*)(smem[cur] + p * 384 + ((kk * 64 + lhi * 16) ^ ((p & 7) << 4)));
      }
#pragma unroll
      for (int ai = 0; ai < 4; ++ai)
#pragma unroll
        for (int wi = 0; wi < 3; ++wi)
          acc[ai][wi] = (MODE == 2)
              ? __builtin_amdgcn_mfma_f32_16x16x32_bf16(wreg[kk][wi], af[ai], acc[ai][wi], 0, 0, 0)
              : __builtin_amdgcn_mfma_f32_16x16x32_bf16(af[ai], wreg[kk][wi], acc[ai][wi], 0, 0, 0);
    }
    __syncthreads();
    cur ^= 1;

    if (MODE != 2) {
      short* ob = (short*)outp + (size_t)tile * 64 * CC;
#pragma unroll
      for (int wi = 0; wi < 3; ++wi) {
        int o = w * 48 + wi * 16 + lrow;
#pragma unroll
        for (int ai = 0; ai < 4; ++ai)
#pragma unroll
          for (int r = 0; r < 4; ++r) {
            int p = ai * 16 + lhi * 4 + r;
            ob[(size_t)p * CC + o] = f2bf(acc[ai][wi][r] + bw0[wi]);
          }
      }
    } else {
      int bimg = tile / 49, hwbase = (tile - bimg * 49) * 64;
      float* ob = (float*)outp + (size_t)bimg * CC * HW + hwbase;
#pragma unroll
      for (int wi = 0; wi < 3; ++wi)
#pragma unroll
        for (int r = 0; r < 4; ++r) {
          int o = w * 48 + wi * 16 + lhi * 4 + r;
#pragma unroll
          for (int ai = 0; ai < 4; ++ai)
            ob[(size_t)o * HW + ai * 16 + lrow] = acc[ai][wi][r] + bw2[wi][r];
        }
    }
    tile = tnext;
  }
}

// ---------------- gemm2: 768 threads = 12 waves x 16-o slice, T14-split fused xj, GELU ----------------
__global__ void __launch_bounds__(768, 3) gemm2_kernel(
    const __hip_bfloat16* __restrict__ y1g, const __hip_bfloat16* __restrict__ Wf,
    const float* __restrict__ bfv, __hip_bfloat16* __restrict__ outp) {
  __shared__ char smem[2][24576];
  const int t = threadIdx.x;
  const int lane = t & 63, w = t >> 6;        // w in 0..11
  const int lrow = lane & 15, lhi = lane >> 4;
  constexpr int NT = NB * 49;

  int sp[2], sq[2], goff[2];
#pragma unroll
  for (int j = 0; j < 2; ++j) {
    int idx = j * 12288 + t * 16;
    sp[j] = idx / 384;
    sq[j] = idx - sp[j] * 384;
    goff[j] = sp[j] * 384 + (sq[j] ^ ((sp[j] & 7) << 4));
  }

  const float bw = bfv[w * 16 + lrow];

  short8 wreg[2][6];
#pragma unroll
  for (int c = 0; c < 2; ++c)
#pragma unroll
    for (int kk = 0; kk < 6; ++kk) {
      int o = w * 16 + lrow;
      wreg[c][kk] = *(const short8*)((const short*)Wf +
          (size_t)o * 384 + c * 192 + kk * 32 + lhi * 8);
    }

  const int step = gridDim.x;
  int tile = blockIdx.x;
  {
    const char* src = (const char*)y1g + (size_t)tile * 24576;
#pragma unroll
    for (int j = 0; j < 2; ++j)
      gl2lds(src + goff[j], smem[0] + j * 12288 + w * 1024);
  }
  __syncthreads();
  int cur = 0;

  while (tile < NT) {
    const int tnext = tile + step;
    const int bimg = tile / 49;
    const int hwbase = (tile - bimg * 49) * 64;
    const short* y1b = (const short*)y1g + (size_t)bimg * HW * CC;
    f32x4 acc[4] = {};

    // ---- c = 0: ISSUE xj gathers early (regs), MFMA chunk 0, THEN finish xj (T14 split) ----
    short8 nbA[5], nbB[5];
    xj_load(nbA, y1b + (sq[0] >> 1), hwbase + sp[0]);
    xj_load(nbB, y1b + (sq[1] >> 1), hwbase + sp[1]);
#pragma unroll
    for (int kk = 0; kk < 6; ++kk) {
      short8 af[4];
#pragma unroll
      for (int ai = 0; ai < 4; ++ai) {
        int p = ai * 16 + lrow;
        af[ai] = *(const short8*)(smem[cur] + p * 384 + ((kk * 64 + lhi * 16) ^ ((p & 7) << 4)));
      }
#pragma unroll
      for (int ai = 0; ai < 4; ++ai)
        acc[ai] = __builtin_amdgcn_mfma_f32_16x16x32_bf16(af[ai], wreg[0][kk], acc[ai], 0, 0, 0);
    }
    // gather latency has been covered by the MFMA phase; now unpack/max/write
    xj_write(smem[cur ^ 1], nbA, goff[0]);
    xj_write(smem[cur ^ 1], nbB, goff[1]);
    __syncthreads();
    cur ^= 1;

    // ---- c = 1: stage next tile's chunk 0 via gl_lds; compute chunk 1 (xj) ----
    if (tnext < NT) {
      const char* nsrc = (const char*)y1g + (size_t)tnext * 24576;
#pragma unroll
      for (int j = 0; j < 2; ++j)
        gl2lds(nsrc + goff[j], smem[cur ^ 1] + j * 12288 + w * 1024);
    }
#pragma unroll
    for (int kk = 0; kk < 6; ++kk) {
      short8 af[4];
#pragma unroll
      for (int ai = 0; ai < 4; ++ai) {
        int p = ai * 16 + lrow;
        af[ai] = *(const short8*)(smem[cur] + p * 384 + ((kk * 64 + lhi * 16) ^ ((p & 7) << 4)));
      }
#pragma unroll
      for (int ai = 0; ai < 4; ++ai)
        acc[ai] = __builtin_amdgcn_mfma_f32_16x16x32_bf16(af[ai], wreg[1][kk], acc[ai], 0, 0, 0);
    }
    __syncthreads();
    cur ^= 1;

    // ---- epilogue: bias + tanh-GELU -> y2 bf16 pixel-major ----
    short* ob = (short*)outp + (size_t)tile * 64 * CC;
    const int o = w * 16 + lrow;
#pragma unroll
    for (int ai = 0; ai < 4; ++ai)
#pragma unroll
      for (int r = 0; r < 4; ++r) {
        int p = ai * 16 + lhi * 4 + r;
        ob[(size_t)p * CC + o] = f2bf(geluf(acc[ai][r] + bw));
      }
    tile = tnext;
  }
}

extern "C" void kernel_launch(void* const* d_in, const int* in_sizes, int n_in,
                              void* d_out, int out_size, void* d_ws, size_t ws_size,
                              hipStream_t stream) {
  const float* x     = (const float*)d_in[0];
  const float* cpe_w = (const float*)d_in[1];
  const float* cpe_b = (const float*)d_in[2];
  const float* fc1_w = (const float*)d_in[3];
  const float* fc1_b = (const float*)d_in[4];
  const float* bn1_g = (const float*)d_in[5];
  const float* bn1_b = (const float*)d_in[6];
  const float* bn1_m = (const float*)d_in[7];
  const float* bn1_v = (const float*)d_in[8];
  const float* gc_w  = (const float*)d_in[9];
  const float* gc_b  = (const float*)d_in[10];
  const float* bng_g = (const float*)d_in[11];
  const float* bng_b = (const float*)d_in[12];
  const float* bng_m = (const float*)d_in[13];
  const float* bng_v = (const float*)d_in[14];
  const float* fc2_w = (const float*)d_in[15];
  const float* fc2_b = (const float*)d_in[16];
  const float* bn2_g = (const float*)d_in[17];
  const float* bn2_b = (const float*)d_in[18];
  const float* bn2_m = (const float*)d_in[19];
  const float* bn2_v = (const float*)d_in[20];

  if (ws_size < 77594624) return;
  char* ws = (char*)d_ws;
  __hip_bfloat16* W1f = (__hip_bfloat16*)(ws);
  __hip_bfloat16* Wgf = (__hip_bfloat16*)(ws + 73728);
  __hip_bfloat16* W2f = (__hip_bfloat16*)(ws + 221184);
  float* b1f = (float*)(ws + 294912);
  float* bgf = (float*)(ws + 295680);
  float* b2f = (float*)(ws + 296448);
  __hip_bfloat16* y0  = (__hip_bfloat16*)(ws + 524288);       // pixel-major; reused as y2
  __hip_bfloat16* y1  = (__hip_bfloat16*)d_out;               // d_out as bf16 scratch
  float* out = (float*)d_out;

  fold_kernel<<<576, 256, 0, stream>>>(fc1_w, fc1_b, bn1_g, bn1_b, bn1_m, bn1_v,
      gc_w, gc_b, bng_g, bng_b, bng_m, bng_v, fc2_w, fc2_b, bn2_g, bn2_b, bn2_m, bn2_v,
      W1f, Wgf, W2f, b1f, bgf, b2f);
  dwconv_kernel<<<NB * 12 * 7, 256, 0, stream>>>(x, cpe_w, cpe_b, y0);
  gemm_kernel<0><<<512, 256, 0, stream>>>(y0, W1f, b1f, y1);
  gemm2_kernel<<<512, 768, 0, stream>>>(y1, Wgf, bgf, y0);
  gemm_kernel<2><<<512, 256, 0, stream>>>(y0, W2f, b2f, out);
}